// Round 1
// baseline (826.015 us; speedup 1.0000x reference)
//
#include <hip/hip_runtime.h>
#include <hip/hip_bf16.h>

// Sparse (distance-kernel) attention, B=1, L=2048, D=768, H=12, dk=64.
// out0 [L,D] fp32 = context @ Wo^T + bo ; out1 [L,L] fp32 = mean_h attn_weights.
// All matmuls via mfma_f32_16x16x32_bf16 in "NT" form (both operands K-contiguous,
// identical lane->k mapping on A and B => result independent of HW K-permutation).

typedef __bf16 bf16_t;
typedef bf16_t bf16x8 __attribute__((ext_vector_type(8)));
typedef float f32x4 __attribute__((ext_vector_type(4)));

#define L_SEQ 2048
#define DIM 768
#define NH 12
#define DKH 64

// ---- helpers ------------------------------------------------------------

// Stage a 64x64 bf16 tile (row-major, row_stride elems) into LDS [64][72].
// Requires 256 threads. 16B vector loads/stores.
__device__ __forceinline__ void stage64(const bf16_t* __restrict__ src, int row_stride,
                                        bf16_t (*dst)[72], int tid) {
#pragma unroll
  for (int c = 0; c < 2; ++c) {
    int chunk = tid + c * 256;          // 0..511
    int row = chunk >> 3;
    int col = (chunk & 7) * 8;
    *(bf16x8*)&dst[row][col] = *(const bf16x8*)&src[(size_t)row * row_stride + col];
  }
}

// 64x64 = A(64xK=64,row-major LDS) * B(64xK=64,row-major LDS)^T, per-wave 16x64 strip.
// acc[nt][r]: row m = wid*16 + (lane>>4)*4 + r, col n = nt*16 + (lane&15).
__device__ __forceinline__ void mfma_nt64(bf16_t (*As)[72], bf16_t (*Bs)[72],
                                          int wid, int lane, f32x4 acc[4]) {
#pragma unroll
  for (int ks = 0; ks < 2; ++ks) {
    bf16x8 a = *(const bf16x8*)&As[wid * 16 + (lane & 15)][ks * 32 + (lane >> 4) * 8];
#pragma unroll
    for (int nt = 0; nt < 4; ++nt) {
      bf16x8 b = *(const bf16x8*)&Bs[nt * 16 + (lane & 15)][ks * 32 + (lane >> 4) * 8];
      acc[nt] = __builtin_amdgcn_mfma_f32_16x16x32_bf16(a, b, acc[nt], 0, 0, 0);
    }
  }
}

// ---- kernels ------------------------------------------------------------

__global__ void cast_k(const float* __restrict__ in, bf16_t* __restrict__ out, int n) {
  int i = blockIdx.x * 256 + threadIdx.x;
  if (i < n) out[i] = (bf16_t)in[i];
}

// Generic NT GEMM: out[m,n] = sum_k A[m,k]*B[n,k] + bias[n].
// MODE 0: write bf16 head-split layout out[(n>>6)*M*64 + m*64 + (n&63)]  (qkv)
// MODE 1: write fp32 row-major out[m*N + n]                              (final proj)
template <int MODE>
__global__ __launch_bounds__(256) void gemm_nt(const bf16_t* __restrict__ A,
                                               const bf16_t* __restrict__ B,
                                               const float* __restrict__ bias,
                                               void* __restrict__ outp,
                                               int M, int N, int K) {
  __shared__ bf16_t As[64][72];
  __shared__ bf16_t Bs[64][72];
  const int tid = threadIdx.x, wid = tid >> 6, lane = tid & 63;
  const int m0 = blockIdx.y * 64, n0 = blockIdx.x * 64;
  f32x4 acc[4] = {};
  for (int kk = 0; kk < K; kk += 64) {
    __syncthreads();
    stage64(A + (size_t)m0 * K + kk, K, As, tid);
    stage64(B + (size_t)n0 * K + kk, K, Bs, tid);
    __syncthreads();
    mfma_nt64(As, Bs, wid, lane, acc);
  }
  const int r0 = wid * 16 + ((lane >> 4) << 2);
#pragma unroll
  for (int nt = 0; nt < 4; ++nt) {
    int cc = n0 + nt * 16 + (lane & 15);
    float bv = bias[cc];
#pragma unroll
    for (int r = 0; r < 4; ++r) {
      int mm = m0 + r0 + r;
      float val = acc[nt][r] + bv;
      if (MODE == 0) {
        bf16_t* out = (bf16_t*)outp;
        int h = cc >> 6, d = cc & 63;
        out[((size_t)h * M + mm) * 64 + d] = (bf16_t)val;
      } else {
        float* out = (float*)outp;
        out[(size_t)mm * N + cc] = val;
      }
    }
  }
}

// Row sums of squares over dk=64 (from the bf16 values actually fed to MFMA).
__global__ void rownorm(const bf16_t* __restrict__ q, float* __restrict__ qn, int nrows) {
  int row = blockIdx.x * 256 + threadIdx.x;
  if (row >= nrows) return;
  const bf16_t* p = q + (size_t)row * DKH;
  float s = 0.f;
#pragma unroll
  for (int c = 0; c < 8; ++c) {
    bf16x8 v8 = *(const bf16x8*)(p + c * 8);
#pragma unroll
    for (int j = 0; j < 8; ++j) { float f = (float)v8[j]; s = fmaf(f, f, s); }
  }
  qn[row] = s;
}

// vt[h][d][j] = v[h][j][d]
__global__ void transpose_v(const bf16_t* __restrict__ v, bf16_t* __restrict__ vt) {
  int idx = blockIdx.x * 256 + threadIdx.x;
  if (idx >= NH * DKH * L_SEQ) return;
  int j = idx & (L_SEQ - 1);
  int rest = idx >> 11;            // h*64 + d
  int d = rest & 63, h = rest >> 6;
  vt[idx] = v[((size_t)h * L_SEQ + j) * DKH + d];
}

__global__ void init_small(float* dmax) {
  if (threadIdx.x < NH) dmax[threadIdx.x] = 0.f;
}

// Pass: global max of dist_sq per head. dist_sq = max(qn+kn-2*qk,0)/64 >= 0,
// so int-bit atomicMax is order-correct.
__global__ __launch_bounds__(256) void maxdist(const bf16_t* __restrict__ q,
                                               const bf16_t* __restrict__ k,
                                               const float* __restrict__ qn,
                                               const float* __restrict__ kn,
                                               float* __restrict__ dmax) {
  __shared__ bf16_t Qs[64][72];
  __shared__ bf16_t Ks[64][72];
  const int h = blockIdx.z;
  const int i0 = blockIdx.y * 64, j0 = blockIdx.x * 64;
  const int tid = threadIdx.x, wid = tid >> 6, lane = tid & 63;
  stage64(q + ((size_t)h * L_SEQ + i0) * DKH, DKH, Qs, tid);
  stage64(k + ((size_t)h * L_SEQ + j0) * DKH, DKH, Ks, tid);
  __syncthreads();
  f32x4 acc[4] = {};
  mfma_nt64(Qs, Ks, wid, lane, acc);
  const int r0 = wid * 16 + ((lane >> 4) << 2);
  float qnr[4];
#pragma unroll
  for (int r = 0; r < 4; ++r) qnr[r] = qn[h * L_SEQ + i0 + r0 + r];
  float m = 0.f;
#pragma unroll
  for (int nt = 0; nt < 4; ++nt) {
    float knc = kn[h * L_SEQ + j0 + nt * 16 + (lane & 15)];
#pragma unroll
    for (int r = 0; r < 4; ++r)
      m = fmaxf(m, fmaxf(qnr[r] + knc - 2.f * acc[nt][r], 0.f));
  }
  m *= (1.f / 64.f);
#pragma unroll
  for (int s = 1; s < 64; s <<= 1) m = fmaxf(m, __shfl_xor(m, s));
  if (lane == 0) atomicMax((int*)&dmax[h], __float_as_int(m));
}

// Pass: softmax denominators. Note DOUBLE exp: weights = softmax(exp(-ds*dist_norm)).
__global__ __launch_bounds__(256) void denom_k(const bf16_t* __restrict__ q,
                                               const bf16_t* __restrict__ k,
                                               const float* __restrict__ qn,
                                               const float* __restrict__ kn,
                                               const float* __restrict__ dmax,
                                               const float* __restrict__ theta,
                                               float* __restrict__ den) {
  __shared__ bf16_t Qs[64][72];
  __shared__ bf16_t Ks[64][72];
  const int h = blockIdx.y, i0 = blockIdx.x * 64;
  const int tid = threadIdx.x, wid = tid >> 6, lane = tid & 63;
  const float sc = expf(theta[h]) * (1.f / 64.f) / (dmax[h] + 1e-6f);
  stage64(q + ((size_t)h * L_SEQ + i0) * DKH, DKH, Qs, tid);
  const int r0 = wid * 16 + ((lane >> 4) << 2);
  float qnr[4], psum[4] = {0.f, 0.f, 0.f, 0.f};
#pragma unroll
  for (int r = 0; r < 4; ++r) qnr[r] = qn[h * L_SEQ + i0 + r0 + r];
  for (int j0 = 0; j0 < L_SEQ; j0 += 64) {
    __syncthreads();
    stage64(k + ((size_t)h * L_SEQ + j0) * DKH, DKH, Ks, tid);
    __syncthreads();
    f32x4 acc[4] = {};
    mfma_nt64(Qs, Ks, wid, lane, acc);
#pragma unroll
    for (int nt = 0; nt < 4; ++nt) {
      float knc = kn[h * L_SEQ + j0 + nt * 16 + (lane & 15)];
#pragma unroll
      for (int r = 0; r < 4; ++r) {
        float dist = fmaxf(qnr[r] + knc - 2.f * acc[nt][r], 0.f);
        psum[r] += __expf(__expf(-sc * dist));
      }
    }
  }
#pragma unroll
  for (int s = 1; s < 16; s <<= 1)
#pragma unroll
    for (int r = 0; r < 4; ++r) psum[r] += __shfl_xor(psum[r], s);
  if ((lane & 15) == 0)
#pragma unroll
    for (int r = 0; r < 4; ++r) den[h * L_SEQ + i0 + r0 + r] = psum[r];
}

// Pass: context^T[d][i] = sum_j vt[d][j] * w[i][j], per (head, 64-row i-tile).
__global__ __launch_bounds__(256) void context_k(const bf16_t* __restrict__ q,
                                                 const bf16_t* __restrict__ k,
                                                 const bf16_t* __restrict__ vt,
                                                 const float* __restrict__ qn,
                                                 const float* __restrict__ kn,
                                                 const float* __restrict__ dmax,
                                                 const float* __restrict__ theta,
                                                 const float* __restrict__ den,
                                                 bf16_t* __restrict__ ctx) {
  __shared__ bf16_t Qs[64][72];
  __shared__ bf16_t Ks[64][72];
  __shared__ bf16_t Vs[64][72];   // vt tile: rows d, cols j
  __shared__ bf16_t Ws[64][72];   // w tile:  rows i, cols j (bf16)
  const int h = blockIdx.y, i0 = blockIdx.x * 64;
  const int tid = threadIdx.x, wid = tid >> 6, lane = tid & 63;
  const float sc = expf(theta[h]) * (1.f / 64.f) / (dmax[h] + 1e-6f);
  stage64(q + ((size_t)h * L_SEQ + i0) * DKH, DKH, Qs, tid);
  const int r0 = wid * 16 + ((lane >> 4) << 2);
  float qnr[4], invl[4];
#pragma unroll
  for (int r = 0; r < 4; ++r) {
    qnr[r] = qn[h * L_SEQ + i0 + r0 + r];
    invl[r] = 1.f / den[h * L_SEQ + i0 + r0 + r];
  }
  f32x4 cacc[4] = {};
  for (int j0 = 0; j0 < L_SEQ; j0 += 64) {
    __syncthreads();
    stage64(k + ((size_t)h * L_SEQ + j0) * DKH, DKH, Ks, tid);
    stage64(vt + (size_t)h * DKH * L_SEQ + j0, L_SEQ, Vs, tid);
    __syncthreads();
    f32x4 acc[4] = {};
    mfma_nt64(Qs, Ks, wid, lane, acc);
#pragma unroll
    for (int nt = 0; nt < 4; ++nt) {
      float knc = kn[h * L_SEQ + j0 + nt * 16 + (lane & 15)];
#pragma unroll
      for (int r = 0; r < 4; ++r) {
        float dist = fmaxf(qnr[r] + knc - 2.f * acc[nt][r], 0.f);
        float w = __expf(__expf(-sc * dist)) * invl[r];
        Ws[r0 + r][nt * 16 + (lane & 15)] = (bf16_t)w;
      }
    }
    __syncthreads();
    // context^T: A = Vs (m=d strip), B = Ws (n=i), k = j
    mfma_nt64(Vs, Ws, wid, lane, cacc);
  }
  // cacc[nt][r]: d = wid*16+(lane>>4)*4+r, i = i0 + nt*16+(lane&15)
#pragma unroll
  for (int nt = 0; nt < 4; ++nt) {
    int ii = i0 + nt * 16 + (lane & 15);
#pragma unroll
    for (int r = 0; r < 4; ++r) {
      int dd = r0 + r;
      ctx[(size_t)ii * DIM + h * 64 + dd] = (bf16_t)cacc[nt][r];
    }
  }
}

// Pass: out1[i][j] = mean over heads of w_h[i][j].
__global__ __launch_bounds__(256) void attnmean(const bf16_t* __restrict__ q,
                                                const bf16_t* __restrict__ k,
                                                const float* __restrict__ qn,
                                                const float* __restrict__ kn,
                                                const float* __restrict__ dmax,
                                                const float* __restrict__ theta,
                                                const float* __restrict__ den,
                                                float* __restrict__ out1) {
  __shared__ bf16_t Qs[64][72];
  __shared__ bf16_t Ks[64][72];
  const int i0 = blockIdx.y * 64, j0 = blockIdx.x * 64;
  const int tid = threadIdx.x, wid = tid >> 6, lane = tid & 63;
  const int r0 = wid * 16 + ((lane >> 4) << 2);
  float macc[4][4] = {};
  for (int h = 0; h < NH; ++h) {
    const float sc = expf(theta[h]) * (1.f / 64.f) / (dmax[h] + 1e-6f);
    __syncthreads();
    stage64(q + ((size_t)h * L_SEQ + i0) * DKH, DKH, Qs, tid);
    stage64(k + ((size_t)h * L_SEQ + j0) * DKH, DKH, Ks, tid);
    __syncthreads();
    f32x4 acc[4] = {};
    mfma_nt64(Qs, Ks, wid, lane, acc);
    float qnr[4], invl[4];
#pragma unroll
    for (int r = 0; r < 4; ++r) {
      qnr[r] = qn[h * L_SEQ + i0 + r0 + r];
      invl[r] = 1.f / den[h * L_SEQ + i0 + r0 + r];
    }
#pragma unroll
    for (int nt = 0; nt < 4; ++nt) {
      float knc = kn[h * L_SEQ + j0 + nt * 16 + (lane & 15)];
#pragma unroll
      for (int r = 0; r < 4; ++r) {
        float dist = fmaxf(qnr[r] + knc - 2.f * acc[nt][r], 0.f);
        macc[nt][r] += __expf(__expf(-sc * dist)) * invl[r];
      }
    }
  }
#pragma unroll
  for (int nt = 0; nt < 4; ++nt)
#pragma unroll
    for (int r = 0; r < 4; ++r)
      out1[(size_t)(i0 + r0 + r) * L_SEQ + j0 + nt * 16 + (lane & 15)] =
          macc[nt][r] * (1.f / 12.f);
}

// ---- launch -------------------------------------------------------------

extern "C" void kernel_launch(void* const* d_in, const int* in_sizes, int n_in,
                              void* d_out, int out_size, void* d_ws, size_t ws_size,
                              hipStream_t stream) {
  const float* x = (const float*)d_in[0];
  const float* Wq = (const float*)d_in[1];
  const float* bq = (const float*)d_in[2];
  const float* Wk = (const float*)d_in[3];
  const float* bk = (const float*)d_in[4];
  const float* Wv = (const float*)d_in[5];
  const float* bv = (const float*)d_in[6];
  const float* Wo = (const float*)d_in[7];
  const float* bo = (const float*)d_in[8];
  const float* theta = (const float*)d_in[9];

  // workspace layout (~24 MB)
  bf16_t* x_bf = (bf16_t*)d_ws;
  bf16_t* Wq_bf = x_bf + (size_t)L_SEQ * DIM;
  bf16_t* Wk_bf = Wq_bf + (size_t)DIM * DIM;
  bf16_t* Wv_bf = Wk_bf + (size_t)DIM * DIM;
  bf16_t* Wo_bf = Wv_bf + (size_t)DIM * DIM;
  bf16_t* q_bf = Wo_bf + (size_t)DIM * DIM;
  bf16_t* k_bf = q_bf + (size_t)NH * L_SEQ * DKH;
  bf16_t* v_bf = k_bf + (size_t)NH * L_SEQ * DKH;
  bf16_t* vt_bf = v_bf + (size_t)NH * L_SEQ * DKH;
  bf16_t* ctx_bf = vt_bf + (size_t)NH * L_SEQ * DKH;
  float* qn = (float*)(ctx_bf + (size_t)L_SEQ * DIM);
  float* kn = qn + NH * L_SEQ;
  float* den = kn + NH * L_SEQ;
  float* dmax = den + NH * L_SEQ;

  float* out0 = (float*)d_out;
  float* out1 = out0 + (size_t)L_SEQ * DIM;

  cast_k<<<(L_SEQ * DIM) / 256, 256, 0, stream>>>(x, x_bf, L_SEQ * DIM);
  cast_k<<<(DIM * DIM) / 256, 256, 0, stream>>>(Wq, Wq_bf, DIM * DIM);
  cast_k<<<(DIM * DIM) / 256, 256, 0, stream>>>(Wk, Wk_bf, DIM * DIM);
  cast_k<<<(DIM * DIM) / 256, 256, 0, stream>>>(Wv, Wv_bf, DIM * DIM);
  cast_k<<<(DIM * DIM) / 256, 256, 0, stream>>>(Wo, Wo_bf, DIM * DIM);

  dim3 gproj(DIM / 64, L_SEQ / 64);
  gemm_nt<0><<<gproj, 256, 0, stream>>>(x_bf, Wq_bf, bq, q_bf, L_SEQ, DIM, DIM);
  gemm_nt<0><<<gproj, 256, 0, stream>>>(x_bf, Wk_bf, bk, k_bf, L_SEQ, DIM, DIM);
  gemm_nt<0><<<gproj, 256, 0, stream>>>(x_bf, Wv_bf, bv, v_bf, L_SEQ, DIM, DIM);

  rownorm<<<(NH * L_SEQ) / 256, 256, 0, stream>>>(q_bf, qn, NH * L_SEQ);
  rownorm<<<(NH * L_SEQ) / 256, 256, 0, stream>>>(k_bf, kn, NH * L_SEQ);
  transpose_v<<<(NH * DKH * L_SEQ) / 256, 256, 0, stream>>>(v_bf, vt_bf);
  init_small<<<1, 64, 0, stream>>>(dmax);

  maxdist<<<dim3(L_SEQ / 64, L_SEQ / 64, NH), 256, 0, stream>>>(q_bf, k_bf, qn, kn, dmax);
  denom_k<<<dim3(L_SEQ / 64, NH), 256, 0, stream>>>(q_bf, k_bf, qn, kn, dmax, theta, den);
  context_k<<<dim3(L_SEQ / 64, NH), 256, 0, stream>>>(q_bf, k_bf, vt_bf, qn, kn, dmax,
                                                      theta, den, ctx_bf);
  attnmean<<<dim3(L_SEQ / 64, L_SEQ / 64), 256, 0, stream>>>(q_bf, k_bf, qn, kn, dmax,
                                                             theta, den, out1);
  gemm_nt<1><<<gproj, 256, 0, stream>>>(ctx_bf, Wo_bf, bo, out0, L_SEQ, DIM, DIM);
}

// Round 2
// 238.981 us; speedup vs baseline: 3.4564x; 3.4564x over previous
//
#include <hip/hip_runtime.h>
#include <hip/hip_bf16.h>

// Distance-kernel attention, B=1, L=2048, D=768, H=12, dk=64.
// out0 [L,D] fp32 = context @ Wo^T + bo ; out1 [L,L] fp32 = mean_h attn_weights.
// All matmuls via mfma_f32_16x16x32_bf16 in "NT" form (both operands K-contiguous,
// identical lane->k mapping on A and B => result independent of HW K-permutation).

typedef __bf16 bf16_t;
typedef bf16_t bf16x8 __attribute__((ext_vector_type(8)));
typedef float f32x4 __attribute__((ext_vector_type(4)));

#define L_SEQ 2048
#define DIM 768
#define NH 12
#define DKH 64
#define JSPLIT 4   // j-chunks in maxdist pass

// ---- helpers ------------------------------------------------------------

// Stage a 64x64 bf16 tile (row-major, row_stride elems) into LDS [64][72].
// Requires 256 threads. 16B vector loads/stores.
__device__ __forceinline__ void stage64(const bf16_t* __restrict__ src, int row_stride,
                                        bf16_t (*dst)[72], int tid) {
#pragma unroll
  for (int c = 0; c < 2; ++c) {
    int chunk = tid + c * 256;          // 0..511
    int row = chunk >> 3;
    int col = (chunk & 7) * 8;
    *(bf16x8*)&dst[row][col] = *(const bf16x8*)&src[(size_t)row * row_stride + col];
  }
}

// 64x64 = A(64xK=64,row-major LDS) * B(64xK=64,row-major LDS)^T, per-wave 16x64 strip.
// acc[nt][r]: row m = wid*16 + (lane>>4)*4 + r, col n = nt*16 + (lane&15).
__device__ __forceinline__ void mfma_nt64(bf16_t (*As)[72], bf16_t (*Bs)[72],
                                          int wid, int lane, f32x4 acc[4]) {
#pragma unroll
  for (int ks = 0; ks < 2; ++ks) {
    bf16x8 a = *(const bf16x8*)&As[wid * 16 + (lane & 15)][ks * 32 + (lane >> 4) * 8];
#pragma unroll
    for (int nt = 0; nt < 4; ++nt) {
      bf16x8 b = *(const bf16x8*)&Bs[nt * 16 + (lane & 15)][ks * 32 + (lane >> 4) * 8];
      acc[nt] = __builtin_amdgcn_mfma_f32_16x16x32_bf16(a, b, acc[nt], 0, 0, 0);
    }
  }
}

// ---- kernels ------------------------------------------------------------

__global__ void cast_k(const float* __restrict__ in, bf16_t* __restrict__ out, int n4) {
  int i = blockIdx.x * 256 + threadIdx.x;
  if (i >= n4) return;
  float4 v = ((const float4*)in)[i];
  bf16_t* o = out + (size_t)i * 4;
  o[0] = (bf16_t)v.x; o[1] = (bf16_t)v.y; o[2] = (bf16_t)v.z; o[3] = (bf16_t)v.w;
}

// Generic NT GEMM: out[m,n] = sum_k A[m,k]*B[n,k] + bias[n].
// MODE 0: q/k — bf16 head-split out[h][m][d], plus row sum-of-squares -> norm[h*L+m]
// MODE 1: v  — bf16 transposed out vt[(h*64+d)][m]
// MODE 2: fp32 row-major out[m*N + n]  (final projection)
template <int MODE>
__global__ __launch_bounds__(256) void gemm_nt(const bf16_t* __restrict__ A,
                                               const bf16_t* __restrict__ B,
                                               const float* __restrict__ bias,
                                               void* __restrict__ outp,
                                               float* __restrict__ norm,
                                               int M, int N, int K) {
  __shared__ bf16_t As[64][72];
  __shared__ bf16_t Bs[64][72];
  const int tid = threadIdx.x, wid = tid >> 6, lane = tid & 63;
  const int m0 = blockIdx.y * 64, n0 = blockIdx.x * 64;
  f32x4 acc[4] = {};
  for (int kk = 0; kk < K; kk += 64) {
    __syncthreads();
    stage64(A + (size_t)m0 * K + kk, K, As, tid);
    stage64(B + (size_t)n0 * K + kk, K, Bs, tid);
    __syncthreads();
    mfma_nt64(As, Bs, wid, lane, acc);
  }
  const int r0 = wid * 16 + ((lane >> 4) << 2);
  float ss[4] = {0.f, 0.f, 0.f, 0.f};
#pragma unroll
  for (int nt = 0; nt < 4; ++nt) {
    int cc = n0 + nt * 16 + (lane & 15);
    float bv = bias[cc];
#pragma unroll
    for (int r = 0; r < 4; ++r) {
      int mm = m0 + r0 + r;
      float val = acc[nt][r] + bv;
      if (MODE == 0) {
        bf16_t* out = (bf16_t*)outp;
        int h = cc >> 6, d = cc & 63;
        out[((size_t)h * M + mm) * 64 + d] = (bf16_t)val;
        ss[r] = fmaf(val, val, ss[r]);
      } else if (MODE == 1) {
        bf16_t* out = (bf16_t*)outp;
        out[(size_t)cc * M + mm] = (bf16_t)val;   // vt[h*64+d][m]
      } else {
        float* out = (float*)outp;
        out[(size_t)mm * N + cc] = val;
      }
    }
  }
  if (MODE == 0) {
    // full dk=64 row sums: reduce across the 16-lane col group
#pragma unroll
    for (int s = 1; s < 16; s <<= 1)
#pragma unroll
      for (int r = 0; r < 4; ++r) ss[r] += __shfl_xor(ss[r], s);
    if ((lane & 15) == 0) {
      int h = n0 >> 6;
#pragma unroll
      for (int r = 0; r < 4; ++r) norm[h * M + m0 + r0 + r] = ss[r];
    }
  }
}

// Pass 1: per-block max of dist_sq. grid (i-tiles, JSPLIT, NH).
// blockmax[(h*JSPLIT + jc)*32 + it] — no atomics.
__global__ __launch_bounds__(256) void maxdist(const bf16_t* __restrict__ q,
                                               const bf16_t* __restrict__ k,
                                               const float* __restrict__ qn,
                                               const float* __restrict__ kn,
                                               float* __restrict__ blockmax) {
  __shared__ bf16_t Qs[64][72];
  __shared__ bf16_t Ks[64][72];
  __shared__ float wmax[4];
  const int it = blockIdx.x, jc = blockIdx.y, h = blockIdx.z;
  const int i0 = it * 64;
  const int tid = threadIdx.x, wid = tid >> 6, lane = tid & 63;
  stage64(q + ((size_t)h * L_SEQ + i0) * DKH, DKH, Qs, tid);
  const int r0 = wid * 16 + ((lane >> 4) << 2);
  float qnr[4];
#pragma unroll
  for (int r = 0; r < 4; ++r) qnr[r] = qn[h * L_SEQ + i0 + r0 + r];
  float m = 0.f;
  const int jtiles = L_SEQ / 64 / JSPLIT;
  for (int jt = 0; jt < jtiles; ++jt) {
    int j0 = (jc * jtiles + jt) * 64;
    __syncthreads();
    stage64(k + ((size_t)h * L_SEQ + j0) * DKH, DKH, Ks, tid);
    __syncthreads();
    f32x4 acc[4] = {};
    mfma_nt64(Qs, Ks, wid, lane, acc);
#pragma unroll
    for (int nt = 0; nt < 4; ++nt) {
      float knc = kn[h * L_SEQ + j0 + nt * 16 + (lane & 15)];
#pragma unroll
      for (int r = 0; r < 4; ++r)
        m = fmaxf(m, fmaxf(qnr[r] + knc - 2.f * acc[nt][r], 0.f));
    }
  }
#pragma unroll
  for (int s = 1; s < 64; s <<= 1) m = fmaxf(m, __shfl_xor(m, s));
  if (lane == 0) wmax[wid] = m;
  __syncthreads();
  if (tid == 0) {
    float bm = fmaxf(fmaxf(wmax[0], wmax[1]), fmaxf(wmax[2], wmax[3]));
    blockmax[(h * JSPLIT + jc) * (L_SEQ / 64) + it] = bm * (1.f / 64.f);
  }
}

// Reduce blockmax -> dmax[h]. NH blocks x 128 threads.
__global__ void reduce_dmax(const float* __restrict__ blockmax, float* __restrict__ dmax) {
  __shared__ float wm[2];
  const int h = blockIdx.x, tid = threadIdx.x, lane = tid & 63, wid = tid >> 6;
  float m = blockmax[h * 128 + tid];
#pragma unroll
  for (int s = 1; s < 64; s <<= 1) m = fmaxf(m, __shfl_xor(m, s));
  if (lane == 0) wm[wid] = m;
  __syncthreads();
  if (tid == 0) dmax[h] = fmaxf(wm[0], wm[1]);
}

// Pass 2 (fused): online denominator + unnormalized context, normalize at end.
// grid (i-tiles, NH).
__global__ __launch_bounds__(256) void fusedctx(const bf16_t* __restrict__ q,
                                                const bf16_t* __restrict__ k,
                                                const bf16_t* __restrict__ vt,
                                                const float* __restrict__ qn,
                                                const float* __restrict__ kn,
                                                const float* __restrict__ dmax,
                                                const float* __restrict__ theta,
                                                float* __restrict__ den,
                                                bf16_t* __restrict__ ctx) {
  __shared__ bf16_t Qs[64][72];
  __shared__ bf16_t Ks[64][72];
  __shared__ bf16_t Vs[64][72];   // vt tile: rows d, cols j
  __shared__ bf16_t Ws[64][72];   // w tile:  rows i, cols j (bf16, unnormalized)
  __shared__ float denL[64];
  const int h = blockIdx.y, i0 = blockIdx.x * 64;
  const int tid = threadIdx.x, wid = tid >> 6, lane = tid & 63;
  const float sc = expf(theta[h]) * (1.f / 64.f) / (dmax[h] + 1e-6f);
  stage64(q + ((size_t)h * L_SEQ + i0) * DKH, DKH, Qs, tid);
  const int r0 = wid * 16 + ((lane >> 4) << 2);
  float qnr[4], psum[4] = {0.f, 0.f, 0.f, 0.f};
#pragma unroll
  for (int r = 0; r < 4; ++r) qnr[r] = qn[h * L_SEQ + i0 + r0 + r];
  f32x4 cacc[4] = {};
  for (int j0 = 0; j0 < L_SEQ; j0 += 64) {
    __syncthreads();
    stage64(k + ((size_t)h * L_SEQ + j0) * DKH, DKH, Ks, tid);
    stage64(vt + (size_t)h * DKH * L_SEQ + j0, L_SEQ, Vs, tid);
    __syncthreads();
    f32x4 acc[4] = {};
    mfma_nt64(Qs, Ks, wid, lane, acc);
#pragma unroll
    for (int nt = 0; nt < 4; ++nt) {
      float knc = kn[h * L_SEQ + j0 + nt * 16 + (lane & 15)];
#pragma unroll
      for (int r = 0; r < 4; ++r) {
        float dist = fmaxf(qnr[r] + knc - 2.f * acc[nt][r], 0.f);
        float w = __expf(__expf(-sc * dist));   // in [1, e]
        psum[r] += w;
        Ws[r0 + r][nt * 16 + (lane & 15)] = (bf16_t)w;
      }
    }
    __syncthreads();
    // context^T accumulate: A = Vs (m=d strip), B = Ws (n=i), k = j
    mfma_nt64(Vs, Ws, wid, lane, cacc);
  }
  // row denominators: sum across the 16-lane col group
#pragma unroll
  for (int s = 1; s < 16; s <<= 1)
#pragma unroll
    for (int r = 0; r < 4; ++r) psum[r] += __shfl_xor(psum[r], s);
  if ((lane & 15) == 0) {
#pragma unroll
    for (int r = 0; r < 4; ++r) {
      denL[r0 + r] = psum[r];
      den[h * L_SEQ + i0 + r0 + r] = psum[r];
    }
  }
  __syncthreads();
  // cacc[nt][r]: d = r0+r, i = i0 + nt*16+(lane&15)
#pragma unroll
  for (int nt = 0; nt < 4; ++nt) {
    int il = nt * 16 + (lane & 15);
    float inv = 1.f / denL[il];
#pragma unroll
    for (int r = 0; r < 4; ++r)
      ctx[(size_t)(i0 + il) * DIM + h * 64 + r0 + r] = (bf16_t)(cacc[nt][r] * inv);
  }
}

// Pass 3: out1[i][j] = mean over heads of w_h[i][j].
__global__ __launch_bounds__(256) void attnmean(const bf16_t* __restrict__ q,
                                                const bf16_t* __restrict__ k,
                                                const float* __restrict__ qn,
                                                const float* __restrict__ kn,
                                                const float* __restrict__ dmax,
                                                const float* __restrict__ theta,
                                                const float* __restrict__ den,
                                                float* __restrict__ out1) {
  __shared__ bf16_t Qs[64][72];
  __shared__ bf16_t Ks[64][72];
  const int i0 = blockIdx.y * 64, j0 = blockIdx.x * 64;
  const int tid = threadIdx.x, wid = tid >> 6, lane = tid & 63;
  const int r0 = wid * 16 + ((lane >> 4) << 2);
  float macc[4][4] = {};
  for (int h = 0; h < NH; ++h) {
    const float sc = expf(theta[h]) * (1.f / 64.f) / (dmax[h] + 1e-6f);
    __syncthreads();
    stage64(q + ((size_t)h * L_SEQ + i0) * DKH, DKH, Qs, tid);
    stage64(k + ((size_t)h * L_SEQ + j0) * DKH, DKH, Ks, tid);
    __syncthreads();
    f32x4 acc[4] = {};
    mfma_nt64(Qs, Ks, wid, lane, acc);
    float qnr[4], invl[4];
#pragma unroll
    for (int r = 0; r < 4; ++r) {
      qnr[r] = qn[h * L_SEQ + i0 + r0 + r];
      invl[r] = 1.f / den[h * L_SEQ + i0 + r0 + r];
    }
#pragma unroll
    for (int nt = 0; nt < 4; ++nt) {
      float knc = kn[h * L_SEQ + j0 + nt * 16 + (lane & 15)];
#pragma unroll
      for (int r = 0; r < 4; ++r) {
        float dist = fmaxf(qnr[r] + knc - 2.f * acc[nt][r], 0.f);
        macc[nt][r] += __expf(__expf(-sc * dist)) * invl[r];
      }
    }
  }
#pragma unroll
  for (int nt = 0; nt < 4; ++nt)
#pragma unroll
    for (int r = 0; r < 4; ++r)
      out1[(size_t)(i0 + r0 + r) * L_SEQ + j0 + nt * 16 + (lane & 15)] =
          macc[nt][r] * (1.f / 12.f);
}

// ---- launch -------------------------------------------------------------

extern "C" void kernel_launch(void* const* d_in, const int* in_sizes, int n_in,
                              void* d_out, int out_size, void* d_ws, size_t ws_size,
                              hipStream_t stream) {
  const float* x = (const float*)d_in[0];
  const float* Wq = (const float*)d_in[1];
  const float* bq = (const float*)d_in[2];
  const float* Wk = (const float*)d_in[3];
  const float* bk = (const float*)d_in[4];
  const float* Wv = (const float*)d_in[5];
  const float* bv = (const float*)d_in[6];
  const float* Wo = (const float*)d_in[7];
  const float* bo = (const float*)d_in[8];
  const float* theta = (const float*)d_in[9];

  // workspace layout (~20 MB)
  bf16_t* x_bf = (bf16_t*)d_ws;
  bf16_t* Wq_bf = x_bf + (size_t)L_SEQ * DIM;
  bf16_t* Wk_bf = Wq_bf + (size_t)DIM * DIM;
  bf16_t* Wv_bf = Wk_bf + (size_t)DIM * DIM;
  bf16_t* Wo_bf = Wv_bf + (size_t)DIM * DIM;
  bf16_t* q_bf = Wo_bf + (size_t)DIM * DIM;
  bf16_t* k_bf = q_bf + (size_t)NH * L_SEQ * DKH;
  bf16_t* vt_bf = k_bf + (size_t)NH * L_SEQ * DKH;
  bf16_t* ctx_bf = vt_bf + (size_t)NH * L_SEQ * DKH;
  float* qn = (float*)(ctx_bf + (size_t)L_SEQ * DIM);
  float* kn = qn + NH * L_SEQ;
  float* den = kn + NH * L_SEQ;
  float* dmax = den + NH * L_SEQ;
  float* blockmax = dmax + 64;          // NH * JSPLIT * 32 = 1536

  float* out0 = (float*)d_out;
  float* out1 = out0 + (size_t)L_SEQ * DIM;

  cast_k<<<(L_SEQ * DIM / 4 + 255) / 256, 256, 0, stream>>>(x, x_bf, L_SEQ * DIM / 4);
  cast_k<<<(DIM * DIM / 4 + 255) / 256, 256, 0, stream>>>(Wq, Wq_bf, DIM * DIM / 4);
  cast_k<<<(DIM * DIM / 4 + 255) / 256, 256, 0, stream>>>(Wk, Wk_bf, DIM * DIM / 4);
  cast_k<<<(DIM * DIM / 4 + 255) / 256, 256, 0, stream>>>(Wv, Wv_bf, DIM * DIM / 4);
  cast_k<<<(DIM * DIM / 4 + 255) / 256, 256, 0, stream>>>(Wo, Wo_bf, DIM * DIM / 4);

  dim3 gproj(DIM / 64, L_SEQ / 64);
  gemm_nt<0><<<gproj, 256, 0, stream>>>(x_bf, Wq_bf, bq, q_bf, qn, L_SEQ, DIM, DIM);
  gemm_nt<0><<<gproj, 256, 0, stream>>>(x_bf, Wk_bf, bk, k_bf, kn, L_SEQ, DIM, DIM);
  gemm_nt<1><<<gproj, 256, 0, stream>>>(x_bf, Wv_bf, bv, vt_bf, nullptr, L_SEQ, DIM, DIM);

  maxdist<<<dim3(L_SEQ / 64, JSPLIT, NH), 256, 0, stream>>>(q_bf, k_bf, qn, kn, blockmax);
  reduce_dmax<<<NH, 128, 0, stream>>>(blockmax, dmax);
  fusedctx<<<dim3(L_SEQ / 64, NH), 256, 0, stream>>>(q_bf, k_bf, vt_bf, qn, kn, dmax,
                                                     theta, den, ctx_bf);
  attnmean<<<dim3(L_SEQ / 64, L_SEQ / 64), 256, 0, stream>>>(q_bf, k_bf, qn, kn, dmax,
                                                             theta, den, out1);
  gemm_nt<2><<<gproj, 256, 0, stream>>>(ctx_bf, Wo_bf, bo, out0, nullptr, L_SEQ, DIM, DIM);
}